// Round 1
// baseline (825.090 us; speedup 1.0000x reference)
//
#include <hip/hip_runtime.h>

#define B_ 2
#define N_ 1024
#define FS_ 1024
#define FZ_ 64
#define H_ 16
#define C_ 64

using bf16x8 = __attribute__((ext_vector_type(8))) short;
using f32x4  = __attribute__((ext_vector_type(4))) float;

__device__ inline short f2bf(float x) {
    unsigned int u = __float_as_uint(x);
    unsigned int r = (u + 0x7fffu + ((u >> 16) & 1u)) >> 16;
    return (short)r;
}

// ---------------- Kernel 1: QKV projection (bf16 MFMA) + RoPE ----------------
// C[M=2048][N=3072] = s[2048][1024] @ [Wq|Wk|Wv]. 128x128 block tile, 4 waves
// (2x2 of 64x64), BK=32, mfma_f32_16x16x32_bf16.
// A-frag: A[m=lane&15][k=quad*8+j]; B-frag: B[k=quad*8+j][n=lane&15];
// D: row=quad*4+reg, col=lane&15  (m89/m91-verified layouts).
__global__ __launch_bounds__(256) void qkv_rope_kernel(
    const float* __restrict__ s, const float* __restrict__ Wq,
    const float* __restrict__ Wk, const float* __restrict__ Wv,
    const int* __restrict__ positions,
    short* __restrict__ Qb, short* __restrict__ Kb, short* __restrict__ Vt)
{
    const int m0  = blockIdx.x * 128;
    const int by  = blockIdx.y;
    const int mat = by >> 3;                 // 0=Q,1=K,2=V
    const int n0  = (by & 7) * 128;
    const float* W = (mat == 0) ? Wq : (mat == 1) ? Wk : Wv;

    __shared__ __align__(16) short As[128 * 40];   // [m][k], k padded 32->40
    __shared__ __align__(16) short Bs[128 * 40];   // [n][k] (transposed), padded

    const int tid  = threadIdx.x;
    const int wid  = tid >> 6;
    const int lane = tid & 63;
    const int l15  = lane & 15;
    const int quad = lane >> 4;
    const int wm   = (wid & 1) * 64;
    const int wn   = (wid >> 1) * 64;

    f32x4 acc[4][4] = {};

    const int tk4 = tid & 7;    // A staging: k/4
    const int tm  = tid >> 3;   // A staging: m (0..31)
    const int tn4 = tid & 31;   // B staging: n/4
    const int tk  = tid >> 5;   // B staging: k (0..7)

    for (int k0 = 0; k0 < FS_; k0 += 32) {
        // stage A (f32 -> bf16)
        #pragma unroll
        for (int i = 0; i < 4; i++) {
            int mrow = tm + 32 * i;
            const float4 v = *reinterpret_cast<const float4*>(
                &s[(size_t)(m0 + mrow) * FS_ + k0 + tk4 * 4]);
            short4 h;
            h.x = f2bf(v.x); h.y = f2bf(v.y); h.z = f2bf(v.z); h.w = f2bf(v.w);
            *reinterpret_cast<short4*>(&As[mrow * 40 + tk4 * 4]) = h;
        }
        // stage B transposed (k-contiguous rows so b-frags are ds_read_b128)
        #pragma unroll
        for (int i = 0; i < 4; i++) {
            int krow = tk + 8 * i;
            const float4 v = *reinterpret_cast<const float4*>(
                &W[(size_t)(k0 + krow) * 1024 + n0 + tn4 * 4]);
            Bs[(tn4 * 4 + 0) * 40 + krow] = f2bf(v.x);
            Bs[(tn4 * 4 + 1) * 40 + krow] = f2bf(v.y);
            Bs[(tn4 * 4 + 2) * 40 + krow] = f2bf(v.z);
            Bs[(tn4 * 4 + 3) * 40 + krow] = f2bf(v.w);
        }
        __syncthreads();
        bf16x8 a[4], b[4];
        #pragma unroll
        for (int mi = 0; mi < 4; mi++)
            a[mi] = *reinterpret_cast<const bf16x8*>(&As[(wm + mi * 16 + l15) * 40 + quad * 8]);
        #pragma unroll
        for (int ni = 0; ni < 4; ni++)
            b[ni] = *reinterpret_cast<const bf16x8*>(&Bs[(wn + ni * 16 + l15) * 40 + quad * 8]);
        #pragma unroll
        for (int mi = 0; mi < 4; mi++)
            #pragma unroll
            for (int ni = 0; ni < 4; ni++)
                acc[mi][ni] = __builtin_amdgcn_mfma_f32_16x16x32_bf16(a[mi], b[ni], acc[mi][ni], 0, 0, 0);
        __syncthreads();
    }

    const int h = (n0 + wn) >> 6;   // head (wave spans exactly one head's 64 cols)

    if (mat < 2) {
        short* dst = (mat == 0) ? Qb : Kb;
        float inv_ts[2];
        #pragma unroll
        for (int ni = 0; ni < 2; ni++) {
            float c1 = (float)(ni * 16 + l15);               // c in [0,32)
            inv_ts[ni] = __expf(-(c1 / 32.f) * 9.210340371976184f); // 10000^(-c/32)
        }
        #pragma unroll
        for (int mi = 0; mi < 4; mi++) {
            #pragma unroll
            for (int r = 0; r < 4; r++) {
                int row = m0 + wm + mi * 16 + quad * 4 + r;
                float pos = (float)positions[row];
                size_t base = (size_t)row * 1024 + n0 + wn;
                #pragma unroll
                for (int ni = 0; ni < 2; ni++) {
                    float sn, cs;
                    __sincosf(pos * inv_ts[ni], &sn, &cs);
                    float x1 = acc[mi][ni][r], x2 = acc[mi][ni + 2][r];
                    dst[base + ni * 16 + l15]       = f2bf(x1 * cs - x2 * sn);
                    dst[base + (ni + 2) * 16 + l15] = f2bf(x2 * cs + x1 * sn);
                }
            }
        }
    } else {
        // V stored transposed: Vt[(b*H + h)*C + c][n]  (PV b-frags k-contiguous)
        #pragma unroll
        for (int mi = 0; mi < 4; mi++) {
            #pragma unroll
            for (int r = 0; r < 4; r++) {
                int row = m0 + wm + mi * 16 + quad * 4 + r;
                int bb = row >> 10, nn = row & 1023;
                #pragma unroll
                for (int ni = 0; ni < 4; ni++) {
                    int c = ni * 16 + l15;
                    Vt[(size_t)((bb * H_ + h) * C_ + c) * N_ + nn] = f2bf(acc[mi][ni][r]);
                }
            }
        }
    }
}

// ---------------- Kernel 2: fused bias + flash attention ----------------
// Block = (b, q-tile of 16, head-group of 4). 256 threads = 4 waves, 1 head/wave.
// Per k-tile (32): cooperatively compute bias[q][k][4h] into LDS from pair
// (streamed, never materialized), then per-wave QK^T mfma, online softmax,
// P->LDS->A-layout, PV mfma.
#define TQ 16
#define TK 32

__global__ __launch_bounds__(256) void attn_kernel(
    const short* __restrict__ Qb, const short* __restrict__ Kb,
    const short* __restrict__ Vt, const float* __restrict__ pair,
    const float* __restrict__ Wb, const int* __restrict__ seg,
    float* __restrict__ out)
{
    const int bid = blockIdx.x;
    const int hg  = bid & 3;
    const int b   = (bid >> 2) & 1;
    const int j   = bid >> 3;                    // 0..63
    const int qt  = (j < 32) ? j : 95 - j;       // triangle load-balance swizzle
    const int q0  = qt * TQ;

    const int tid  = threadIdx.x;
    const int wid  = tid >> 6;
    const int lane = tid & 63;
    const int l15  = lane & 15;
    const int quad = lane >> 4;
    const int h    = hg * 4 + wid;

    __shared__ __align__(16) float biasS[TQ * TK * 5];  // [q][k][h(4)+pad]
    __shared__ float WbS[FZ_ * H_];
    __shared__ __align__(16) short Ps[4][TQ * 40];      // per-wave P, padded rows
    __shared__ int segqS[TQ];
    __shared__ int segkS[TK];

    for (int i = tid; i < FZ_ * H_; i += 256) WbS[i] = Wb[i];
    if (tid < TQ) segqS[tid] = seg[b * N_ + q0 + tid];
    __syncthreads();

    // Q fragments (RoPE already applied), A-layout: m=l15, k=quad*8+j
    bf16x8 qa[2];
    #pragma unroll
    for (int ks = 0; ks < 2; ks++)
        qa[ks] = *reinterpret_cast<const bf16x8*>(
            &Qb[(size_t)(b * N_ + q0 + l15) * 1024 + h * 64 + ks * 32 + quad * 8]);

    f32x4 O[4] = {};
    float m_i[4], l_i[4];
    #pragma unroll
    for (int r = 0; r < 4; r++) { m_i[r] = -1e30f; l_i[r] = 0.f; }

    const int seg_q0 = seg[b * N_ + q0];
    const int ktmax  = (q0 + TQ - 1) >> 5;
    const float sm_scale = 0.125f;

    for (int kt = 0; kt <= ktmax; kt++) {
        const int k0 = kt * TK;
        // segment skip: segments sorted -> tile fully masked iff max seg_k < min seg_q
        if (seg[b * N_ + k0 + TK - 1] < seg_q0) continue;

        __syncthreads();
        if (tid < TK) segkS[tid] = seg[b * N_ + k0 + tid];
        // bias tile: 512 (q,k) pairs, 2 per thread, 4 heads each
        #pragma unroll
        for (int pp = 0; pp < 2; pp++) {
            int p  = tid + pp * 256;
            int qq = p >> 5, kk = p & 31;
            const float* pv = &pair[((size_t)(b * N_ + q0 + qq) * N_ + k0 + kk) * FZ_];
            float acc4[4] = {0.f, 0.f, 0.f, 0.f};
            #pragma unroll
            for (int f = 0; f < FZ_; f += 4) {
                float4 pf = *reinterpret_cast<const float4*>(&pv[f]);
                #pragma unroll
                for (int hh = 0; hh < 4; hh++) {
                    const float* wc = &WbS[f * H_ + hg * 4 + hh];
                    acc4[hh] += pf.x * wc[0] + pf.y * wc[H_] + pf.z * wc[2 * H_] + pf.w * wc[3 * H_];
                }
            }
            #pragma unroll
            for (int hh = 0; hh < 4; hh++) biasS[p * 5 + hh] = acc4[hh];
        }
        __syncthreads();

        // QK^T: S[16 q][32 k] per head
        f32x4 S[2] = {};
        #pragma unroll
        for (int ni = 0; ni < 2; ni++)
            #pragma unroll
            for (int ks = 0; ks < 2; ks++) {
                bf16x8 kb = *reinterpret_cast<const bf16x8*>(
                    &Kb[(size_t)(b * N_ + k0 + ni * 16 + l15) * 1024 + h * 64 + ks * 32 + quad * 8]);
                S[ni] = __builtin_amdgcn_mfma_f32_16x16x32_bf16(qa[ks], kb, S[ni], 0, 0, 0);
            }

        float x[2][4], rm[4];
        #pragma unroll
        for (int r = 0; r < 4; r++) {
            int ql = quad * 4 + r;
            int qg = q0 + ql;
            int sq = segqS[ql];
            #pragma unroll
            for (int ni = 0; ni < 2; ni++) {
                int kc = ni * 16 + l15;
                int kg = k0 + kc;
                bool ok = (kg <= qg) && (segkS[kc] == sq);
                float xv = S[ni][r] * sm_scale + biasS[(ql * TK + kc) * 5 + wid];
                x[ni][r] = ok ? xv : -1e30f;
            }
            rm[r] = fmaxf(x[0][r], x[1][r]);
        }
        #pragma unroll
        for (int off = 1; off < 16; off <<= 1)
            #pragma unroll
            for (int r = 0; r < 4; r++)
                rm[r] = fmaxf(rm[r], __shfl_xor(rm[r], off, 64));

        float rs[4];
        #pragma unroll
        for (int r = 0; r < 4; r++) {
            float mn    = fmaxf(m_i[r], rm[r]);
            float alpha = __expf(m_i[r] - mn);
            float p0 = __expf(x[0][r] - mn);
            float p1 = __expf(x[1][r] - mn);
            Ps[wid][(quad * 4 + r) * 40 + l15]      = f2bf(p0);
            Ps[wid][(quad * 4 + r) * 40 + 16 + l15] = f2bf(p1);
            rs[r]  = p0 + p1;
            m_i[r] = mn;
            l_i[r] *= alpha;
            #pragma unroll
            for (int ni = 0; ni < 4; ni++) O[ni][r] *= alpha;
        }
        #pragma unroll
        for (int off = 1; off < 16; off <<= 1)
            #pragma unroll
            for (int r = 0; r < 4; r++)
                rs[r] += __shfl_xor(rs[r], off, 64);
        #pragma unroll
        for (int r = 0; r < 4; r++) l_i[r] += rs[r];

        __syncthreads();   // drain P writes (lgkmcnt) before A-layout re-read

        bf16x8 ap = *reinterpret_cast<const bf16x8*>(&Ps[wid][l15 * 40 + quad * 8]);
        #pragma unroll
        for (int ni = 0; ni < 4; ni++) {
            bf16x8 vb = *reinterpret_cast<const bf16x8*>(
                &Vt[(size_t)((b * H_ + h) * C_ + ni * 16 + l15) * N_ + k0 + quad * 8]);
            O[ni] = __builtin_amdgcn_mfma_f32_16x16x32_bf16(ap, vb, O[ni], 0, 0, 0);
        }
    }

    #pragma unroll
    for (int r = 0; r < 4; r++) {
        float inv = 1.f / l_i[r];
        int qg = q0 + quad * 4 + r;
        #pragma unroll
        for (int ni = 0; ni < 4; ni++)
            out[(size_t)((b * N_ + qg) * H_ + h) * C_ + ni * 16 + l15] = O[ni][r] * inv;
    }
}

extern "C" void kernel_launch(void* const* d_in, const int* in_sizes, int n_in,
                              void* d_out, int out_size, void* d_ws, size_t ws_size,
                              hipStream_t stream) {
    const float* s    = (const float*)d_in[0];
    const float* pair = (const float*)d_in[1];
    const int*   seg  = (const int*)d_in[2];
    const int*   pos  = (const int*)d_in[3];
    const float* Wq   = (const float*)d_in[4];
    const float* Wk   = (const float*)d_in[5];
    const float* Wv   = (const float*)d_in[6];
    const float* Wb   = (const float*)d_in[7];
    float* out = (float*)d_out;

    short* Qb = (short*)d_ws;                    // 2048x1024 bf16 = 4 MiB
    short* Kb = Qb + (size_t)2048 * 1024;        // 4 MiB
    short* Vt = Kb + (size_t)2048 * 1024;        // 4 MiB, layout [b][h][c][n]

    qkv_rope_kernel<<<dim3(16, 24), 256, 0, stream>>>(s, Wq, Wk, Wv, pos, Qb, Kb, Vt);
    attn_kernel<<<dim3(512), 256, 0, stream>>>(Qb, Kb, Vt, pair, Wb, seg, out);
}

// Round 2
// 668.208 us; speedup vs baseline: 1.2348x; 1.2348x over previous
//
#include <hip/hip_runtime.h>

#define B_ 2
#define N_ 1024
#define FS_ 1024
#define FZ_ 64
#define H_ 16
#define C_ 64

using bf16x8 = __attribute__((ext_vector_type(8))) short;
using f32x4  = __attribute__((ext_vector_type(4))) float;

typedef __attribute__((address_space(3))) unsigned int lds_u32;
typedef __attribute__((address_space(1))) unsigned int glb_u32;

__device__ __forceinline__ void glds16(const void* g, void* l) {
    __builtin_amdgcn_global_load_lds((const glb_u32*)g, (lds_u32*)l, 16, 0, 0);
}

__device__ inline short f2bf(float x) {
    unsigned int u = __float_as_uint(x);
    unsigned int r = (u + 0x7fffu + ((u >> 16) & 1u)) >> 16;
    return (short)r;
}

// ---------------- conv_s: s f32 [2048][1024] -> bf16 same layout ----------------
__global__ __launch_bounds__(256) void conv_s_kernel(const float* __restrict__ s,
                                                     short* __restrict__ sB) {
    int i = (blockIdx.x * 256 + threadIdx.x) * 8;
    float4 v0 = *reinterpret_cast<const float4*>(&s[i]);
    float4 v1 = *reinterpret_cast<const float4*>(&s[i + 4]);
    bf16x8 o;
    o[0] = f2bf(v0.x); o[1] = f2bf(v0.y); o[2] = f2bf(v0.z); o[3] = f2bf(v0.w);
    o[4] = f2bf(v1.x); o[5] = f2bf(v1.y); o[6] = f2bf(v1.z); o[7] = f2bf(v1.w);
    *reinterpret_cast<bf16x8*>(&sB[i]) = o;
}

// ---------------- conv_w: [Wq|Wk|Wv] f32 [1024 k][1024 n] -> WT bf16 [3072 n][1024 k]
__global__ __launch_bounds__(256) void conv_w_kernel(const float* __restrict__ Wq,
                                                     const float* __restrict__ Wk,
                                                     const float* __restrict__ Wv,
                                                     short* __restrict__ WT) {
    const int mat = blockIdx.z;
    const float* W = (mat == 0) ? Wq : (mat == 1) ? Wk : Wv;
    const int k0 = blockIdx.x * 32, n0 = blockIdx.y * 32;
    __shared__ float tl[32][33];
    const int t = threadIdx.x;
    {
        int kr = t >> 3, nq = t & 7;
        float4 v = *reinterpret_cast<const float4*>(&W[(size_t)(k0 + kr) * 1024 + n0 + nq * 4]);
        tl[kr][nq * 4 + 0] = v.x; tl[kr][nq * 4 + 1] = v.y;
        tl[kr][nq * 4 + 2] = v.z; tl[kr][nq * 4 + 3] = v.w;
    }
    __syncthreads();
    int n = t >> 3, kq = t & 7;
    short4 o;
    o.x = f2bf(tl[kq * 4 + 0][n]); o.y = f2bf(tl[kq * 4 + 1][n]);
    o.z = f2bf(tl[kq * 4 + 2][n]); o.w = f2bf(tl[kq * 4 + 3][n]);
    *reinterpret_cast<short4*>(&WT[(size_t)(mat * 1024 + n0 + n) * 1024 + k0 + kq * 4]) = o;
}

// ---------------- QKV GEMM (m97 structure) + RoPE epilogue ----------------
// C[2048][3072] = sB[2048][1024] @ WT^T. 128x128 tile, BK=64, global_load_lds 16B.
__global__ __launch_bounds__(256) void qkv_kernel(
    const short* __restrict__ sB, const short* __restrict__ WT,
    const int* __restrict__ positions,
    short* __restrict__ Qb, short* __restrict__ Kb, short* __restrict__ Vt)
{
    const int m0  = blockIdx.x * 128;
    const int n0g = blockIdx.y * 128;

    __shared__ __align__(16) short As[128 * 64];   // [m][k] k-contig, no pad (glds)
    __shared__ __align__(16) short Bs[128 * 64];   // [n][k] k-contig

    const int tid  = threadIdx.x;
    const int wid  = tid >> 6;
    const int lane = tid & 63;
    const int l15  = lane & 15;
    const int quad = lane >> 4;
    const int wm   = (wid & 1) * 64;
    const int wn   = (wid >> 1) * 64;

    f32x4 acc[4][4] = {};

    for (int k0 = 0; k0 < FS_; k0 += 64) {
        #pragma unroll
        for (int rnd = 0; rnd < 4; rnd++) {
            int g = rnd * 256 + tid;
            int m = g >> 3, kq = g & 7;
            glds16(&sB[(size_t)(m0 + m) * 1024 + k0 + kq * 8], &As[g * 8]);
            glds16(&WT[(size_t)(n0g + m) * 1024 + k0 + kq * 8], &Bs[g * 8]);
        }
        __syncthreads();
        #pragma unroll
        for (int ks = 0; ks < 2; ks++) {
            bf16x8 a[4], bb[4];
            #pragma unroll
            for (int mi = 0; mi < 4; mi++)
                a[mi] = *reinterpret_cast<const bf16x8*>(&As[(wm + mi * 16 + l15) * 64 + ks * 32 + quad * 8]);
            #pragma unroll
            for (int ni = 0; ni < 4; ni++)
                bb[ni] = *reinterpret_cast<const bf16x8*>(&Bs[(wn + ni * 16 + l15) * 64 + ks * 32 + quad * 8]);
            #pragma unroll
            for (int mi = 0; mi < 4; mi++)
                #pragma unroll
                for (int ni = 0; ni < 4; ni++)
                    acc[mi][ni] = __builtin_amdgcn_mfma_f32_16x16x32_bf16(a[mi], bb[ni], acc[mi][ni], 0, 0, 0);
        }
        __syncthreads();
    }

    const int mat  = n0g >> 10;
    const int nloc = n0g & 1023;
    const int h    = (nloc + wn) >> 6;

    if (mat < 2) {
        short* dst = (mat == 0) ? Qb : Kb;
        float inv_ts[2];
        #pragma unroll
        for (int ni = 0; ni < 2; ni++) {
            float c1 = (float)(ni * 16 + l15);
            inv_ts[ni] = __expf(-(c1 / 32.f) * 9.210340371976184f); // 10000^(-c/32)
        }
        #pragma unroll
        for (int mi = 0; mi < 4; mi++) {
            #pragma unroll
            for (int r = 0; r < 4; r++) {
                int row = m0 + wm + mi * 16 + quad * 4 + r;
                float pos = (float)positions[row];
                size_t base = (size_t)row * 1024 + nloc + wn;
                #pragma unroll
                for (int ni = 0; ni < 2; ni++) {
                    float sn, cs;
                    __sincosf(pos * inv_ts[ni], &sn, &cs);
                    float x1 = acc[mi][ni][r], x2 = acc[mi][ni + 2][r];
                    dst[base + ni * 16 + l15]       = f2bf(x1 * cs - x2 * sn);
                    dst[base + (ni + 2) * 16 + l15] = f2bf(x2 * cs + x1 * sn);
                }
            }
        }
    } else {
        #pragma unroll
        for (int mi = 0; mi < 4; mi++) {
            #pragma unroll
            for (int r = 0; r < 4; r++) {
                int row = m0 + wm + mi * 16 + quad * 4 + r;
                int bb_ = row >> 10, nn = row & 1023;
                #pragma unroll
                for (int ni = 0; ni < 4; ni++) {
                    int c = ni * 16 + l15;
                    Vt[(size_t)((bb_ * H_ + h) * C_ + c) * N_ + nn] = f2bf(acc[mi][ni][r]);
                }
            }
        }
    }
}

// ---------------- bias GEMM: bias[b][h][q][k] = pair[b,q,k,:] @ Wb ----------------
// One block per live 16x16 (q,k) tile. M=16 heads, N=256 pairs, K=64, MFMA.
__global__ __launch_bounds__(256) void bias_kernel(
    const float* __restrict__ pair, const float* __restrict__ Wb,
    const int* __restrict__ seg, float* __restrict__ biasG)
{
    const int kt = blockIdx.x, qt = blockIdx.y, b = blockIdx.z;
    const int k0 = kt * 16, q0 = qt * 16;
    if (k0 > q0 + 15) return;                                   // fully causal-masked
    if (seg[b * N_ + k0 + 15] < seg[b * N_ + q0]) return;       // fully segment-masked

    __shared__ __align__(16) short pL[256 * 64];   // [pair][f] bf16
    __shared__ __align__(16) short wL[16 * 64];    // [head][f] bf16

    const int tid  = threadIdx.x;
    const int wid  = tid >> 6;
    const int lane = tid & 63;
    const int l15  = lane & 15;
    const int quad = lane >> 4;

    {   // Wb [64 f][16 h] -> wL [h][f]
        float4 v = *reinterpret_cast<const float4*>(&Wb[tid * 4]);
        int f = tid >> 2, hb = (tid & 3) * 4;
        wL[(hb + 0) * 64 + f] = f2bf(v.x);
        wL[(hb + 1) * 64 + f] = f2bf(v.y);
        wL[(hb + 2) * 64 + f] = f2bf(v.z);
        wL[(hb + 3) * 64 + f] = f2bf(v.w);
    }
    #pragma unroll
    for (int rnd = 0; rnd < 16; rnd++) {
        int g = rnd * 256 + tid;
        int p = g >> 4, fq = g & 15;
        int qq = p >> 4, kk = p & 15;
        float4 v = *reinterpret_cast<const float4*>(
            &pair[((size_t)(b * N_ + q0 + qq) * N_ + k0 + kk) * FZ_ + fq * 4]);
        short4 hv;
        hv.x = f2bf(v.x); hv.y = f2bf(v.y); hv.z = f2bf(v.z); hv.w = f2bf(v.w);
        *reinterpret_cast<short4*>(&pL[p * 64 + fq * 4]) = hv;
    }
    __syncthreads();

    bf16x8 a[2];
    a[0] = *reinterpret_cast<const bf16x8*>(&wL[l15 * 64 + quad * 8]);
    a[1] = *reinterpret_cast<const bf16x8*>(&wL[l15 * 64 + 32 + quad * 8]);
    f32x4 acc[4] = {};
    #pragma unroll
    for (int ni = 0; ni < 4; ni++) {
        #pragma unroll
        for (int ks = 0; ks < 2; ks++) {
            bf16x8 bb = *reinterpret_cast<const bf16x8*>(
                &pL[(wid * 64 + ni * 16 + l15) * 64 + ks * 32 + quad * 8]);
            acc[ni] = __builtin_amdgcn_mfma_f32_16x16x32_bf16(a[ks], bb, acc[ni], 0, 0, 0);
        }
    }
    #pragma unroll
    for (int ni = 0; ni < 4; ni++) {
        #pragma unroll
        for (int r = 0; r < 4; r++) {
            int head = quad * 4 + r;
            int p = wid * 64 + ni * 16 + l15;
            int qq = p >> 4, kk = p & 15;
            biasG[((size_t)(b * H_ + head) << 20) + ((size_t)(q0 + qq) << 10) + k0 + kk] = acc[ni][r];
        }
    }
}

// ---------------- flash attention, bias read from global, barrier-free K-loop ----
#define TQ 16
#define TK 64

__global__ __launch_bounds__(256) void attn_kernel(
    const short* __restrict__ Qb, const short* __restrict__ Kb,
    const short* __restrict__ Vt, const float* __restrict__ biasG,
    const int* __restrict__ seg, float* __restrict__ out)
{
    const int bid = blockIdx.x;
    const int hg  = bid & 3;
    const int b   = (bid >> 2) & 1;
    const int j   = bid >> 3;
    const int qt  = (j < 32) ? j : 95 - j;       // triangle load-balance
    const int q0  = qt * TQ;

    const int tid  = threadIdx.x;
    const int wid  = tid >> 6;
    const int lane = tid & 63;
    const int l15  = lane & 15;
    const int quad = lane >> 4;
    const int h    = hg * 4 + wid;

    __shared__ __align__(16) short Ps[4][TQ * 72];   // per-wave: no cross-wave hazard

    bf16x8 qa[2];
    #pragma unroll
    for (int ks = 0; ks < 2; ks++)
        qa[ks] = *reinterpret_cast<const bf16x8*>(
            &Qb[(size_t)(b * N_ + q0 + l15) * 1024 + h * 64 + ks * 32 + quad * 8]);

    int sq[4];
    #pragma unroll
    for (int r = 0; r < 4; r++) sq[r] = seg[b * N_ + q0 + quad * 4 + r];
    const int seg_q0 = seg[b * N_ + q0];

    f32x4 O[4] = {};
    float m_i[4], l_i[4];
    #pragma unroll
    for (int r = 0; r < 4; r++) { m_i[r] = -1e30f; l_i[r] = 0.f; }

    const int ktmax = (q0 + TQ - 1) >> 6;
    const float sm  = 0.125f;
    const float* biasH = biasG + ((size_t)(b * H_ + h) << 20);

    for (int kt = 0; kt <= ktmax; kt++) {
        const int k0 = kt * TK;
        if (seg[b * N_ + k0 + TK - 1] < seg_q0) continue;

        f32x4 S[4] = {};
        #pragma unroll
        for (int ks = 0; ks < 2; ks++)
            #pragma unroll
            for (int ni = 0; ni < 4; ni++) {
                bf16x8 kb = *reinterpret_cast<const bf16x8*>(
                    &Kb[(size_t)(b * N_ + k0 + ni * 16 + l15) * 1024 + h * 64 + ks * 32 + quad * 8]);
                S[ni] = __builtin_amdgcn_mfma_f32_16x16x32_bf16(qa[ks], kb, S[ni], 0, 0, 0);
            }

        int sk[4];
        float bv[4][4];
        #pragma unroll
        for (int ni = 0; ni < 4; ni++) sk[ni] = seg[b * N_ + k0 + ni * 16 + l15];
        #pragma unroll
        for (int ni = 0; ni < 4; ni++)
            #pragma unroll
            for (int r = 0; r < 4; r++)
                bv[ni][r] = biasH[((size_t)(q0 + quad * 4 + r) << 10) + k0 + ni * 16 + l15];

        float x[4][4], rm[4];
        #pragma unroll
        for (int r = 0; r < 4; r++) {
            int qg = q0 + quad * 4 + r;
            rm[r] = -1e30f;
            #pragma unroll
            for (int ni = 0; ni < 4; ni++) {
                int kg = k0 + ni * 16 + l15;
                bool ok = (kg <= qg) && (sk[ni] == sq[r]);
                x[ni][r] = ok ? S[ni][r] * sm + bv[ni][r] : -1e30f;
                rm[r] = fmaxf(rm[r], x[ni][r]);
            }
        }
        #pragma unroll
        for (int off = 1; off < 16; off <<= 1)
            #pragma unroll
            for (int r = 0; r < 4; r++)
                rm[r] = fmaxf(rm[r], __shfl_xor(rm[r], off, 64));

        float rs[4];
        #pragma unroll
        for (int r = 0; r < 4; r++) {
            float mn    = fmaxf(m_i[r], rm[r]);
            float alpha = __expf(m_i[r] - mn);
            float rsum  = 0.f;
            #pragma unroll
            for (int ni = 0; ni < 4; ni++) {
                float p = __expf(x[ni][r] - mn);
                Ps[wid][(quad * 4 + r) * 72 + ni * 16 + l15] = f2bf(p);
                rsum += p;
            }
            rs[r]  = rsum;
            m_i[r] = mn;
            l_i[r] *= alpha;
            #pragma unroll
            for (int ci = 0; ci < 4; ci++) O[ci][r] *= alpha;
        }
        #pragma unroll
        for (int off = 1; off < 16; off <<= 1)
            #pragma unroll
            for (int r = 0; r < 4; r++)
                rs[r] += __shfl_xor(rs[r], off, 64);
        #pragma unroll
        for (int r = 0; r < 4; r++) l_i[r] += rs[r];

        // per-wave LDS: DS ops are in-order within a wave -> no barrier needed
        bf16x8 ap[2];
        ap[0] = *reinterpret_cast<const bf16x8*>(&Ps[wid][l15 * 72 + quad * 8]);
        ap[1] = *reinterpret_cast<const bf16x8*>(&Ps[wid][l15 * 72 + 32 + quad * 8]);
        #pragma unroll
        for (int ci = 0; ci < 4; ci++) {
            #pragma unroll
            for (int ks = 0; ks < 2; ks++) {
                bf16x8 vb = *reinterpret_cast<const bf16x8*>(
                    &Vt[(size_t)((b * H_ + h) * C_ + ci * 16 + l15) * N_ + k0 + ks * 32 + quad * 8]);
                O[ci] = __builtin_amdgcn_mfma_f32_16x16x32_bf16(ap[ks], vb, O[ci], 0, 0, 0);
            }
        }
    }

    #pragma unroll
    for (int r = 0; r < 4; r++) {
        float inv = 1.f / l_i[r];
        int qg = q0 + quad * 4 + r;
        #pragma unroll
        for (int ci = 0; ci < 4; ci++)
            out[(size_t)((b * N_ + qg) * H_ + h) * C_ + ci * 16 + l15] = O[ci][r] * inv;
    }
}

extern "C" void kernel_launch(void* const* d_in, const int* in_sizes, int n_in,
                              void* d_out, int out_size, void* d_ws, size_t ws_size,
                              hipStream_t stream) {
    const float* s    = (const float*)d_in[0];
    const float* pair = (const float*)d_in[1];
    const int*   seg  = (const int*)d_in[2];
    const int*   pos  = (const int*)d_in[3];
    const float* Wq   = (const float*)d_in[4];
    const float* Wk   = (const float*)d_in[5];
    const float* Wv   = (const float*)d_in[6];
    const float* Wb   = (const float*)d_in[7];
    float* out = (float*)d_out;

    short* Qb = (short*)d_ws;                         // 4 MiB
    short* Kb = Qb + (size_t)2048 * 1024;             // 4 MiB
    short* Vt = Kb + (size_t)2048 * 1024;             // 4 MiB  [b][h][c][n]
    short* sB = Vt + (size_t)2048 * 1024;             // 4 MiB
    short* WT = sB + (size_t)2048 * 1024;             // 6 MiB  [3072 n][1024 k]
    float* biasG = (float*)((char*)d_ws + (size_t)22 * 1024 * 1024);  // 128 MiB [b][h][q][k]

    conv_s_kernel<<<1024, 256, 0, stream>>>(s, sB);
    conv_w_kernel<<<dim3(32, 32, 3), 256, 0, stream>>>(Wq, Wk, Wv, WT);
    bias_kernel<<<dim3(64, 64, 2), 256, 0, stream>>>(pair, Wb, seg, biasG);
    qkv_kernel<<<dim3(16, 24), 256, 0, stream>>>(sB, WT, pos, Qb, Kb, Vt);
    attn_kernel<<<dim3(512), 256, 0, stream>>>(Qb, Kb, Vt, biasG, seg, out);
}